// Round 3
// baseline (488.242 us; speedup 1.0000x reference)
//
#include <hip/hip_runtime.h>
#include <hip/hip_bf16.h>

#define NUM_FIELDS 39
#define PER_FIELD_VOCAB 10000
#define EMBED_DIM 128
#define RANK 128
#define BATCH 2048
#define ET_STRIDE 72   // bf16 elems per d-row: 8 swizzled 16B groups + 1 pad group

typedef __bf16 bf16x8 __attribute__((ext_vector_type(8)));
typedef __bf16 bf16x4 __attribute__((ext_vector_type(4)));
typedef float  f32x4  __attribute__((ext_vector_type(4)));
typedef float  f32x4u __attribute__((ext_vector_type(4), aligned(4)));
typedef float  f32x2u __attribute__((ext_vector_type(2), aligned(4)));

// Load one A-fragment (16x16x32 bf16, rows = r, k = f) straight from W (f32,
// row length 39), zero-padded to KPAD=64. kc=0 covers f 0..39-ish (all valid
// for quad*8+7 <= 31); kc=1 covers f 32..63: only quad==0 has data (f 32..38).
__device__ inline bf16x8 load_afrag(const float* __restrict__ Wrow, int quad, int kc) {
    if (kc == 0) {
        f32x4u a = *reinterpret_cast<const f32x4u*>(Wrow + quad * 8);
        f32x4u b = *reinterpret_cast<const f32x4u*>(Wrow + quad * 8 + 4);
        return (bf16x8){(__bf16)a[0], (__bf16)a[1], (__bf16)a[2], (__bf16)a[3],
                        (__bf16)b[0], (__bf16)b[1], (__bf16)b[2], (__bf16)b[3]};
    }
    if (quad == 0) {   // f = 32..38 valid, f = 39 pad
        f32x4u a = *reinterpret_cast<const f32x4u*>(Wrow + 32);
        f32x2u b = *reinterpret_cast<const f32x2u*>(Wrow + 36);
        float  c = Wrow[38];
        return (bf16x8){(__bf16)a[0], (__bf16)a[1], (__bf16)a[2], (__bf16)a[3],
                        (__bf16)b[0], (__bf16)b[1], (__bf16)c, (__bf16)0.f};
    }
    return (bf16x8){(__bf16)0.f, (__bf16)0.f, (__bf16)0.f, (__bf16)0.f,
                    (__bf16)0.f, (__bf16)0.f, (__bf16)0.f, (__bf16)0.f};
}

// ---------------------------------------------------------------------------
// Single fused kernel: one workgroup (256 thr = 4 waves) per batch element.
//   ret[b] = bias + sum_f linear[idx]
//          + sum_{r,d} dp0*dp1 + sum_{r,d} dp2*dp3*dp4,  dp_l = W_l E
// W fragments are loaded directly from global f32 (L1-resident, 40 KB) and
// converted in-register -> no prep kernel, no Wb scratch, one dispatch.
// ---------------------------------------------------------------------------
__global__ __launch_bounds__(256, 6) void tfm_fused(const int* __restrict__ x,
                                                    const float* __restrict__ embed_table,
                                                    const float* __restrict__ linear_table,
                                                    const float* __restrict__ bias,
                                                    const float* __restrict__ W0,
                                                    const float* __restrict__ W1,
                                                    float* __restrict__ out,
                                                    int out_size) {
    __shared__ int sidx[NUM_FIELDS];
    __shared__ __align__(16) __bf16 eT[EMBED_DIM * ET_STRIDE];  // 18432 B, swizzled
    __shared__ float wpart[4];

    const int tid = threadIdx.x;
    const int b   = blockIdx.x;

    if (tid < NUM_FIELDS)
        sidx[tid] = x[b * NUM_FIELDS + tid] + tid * PER_FIELD_VOCAB;
    __syncthreads();

    // Gather emb -> LDS eT[d][f] (bf16, K zero-padded to 64), group-swizzled:
    // logical 16B group fg of row d lives at physical group (fg + 2d) & 7.
    // Store bank-group = 4*((3d + fg) & 7): all 8 groups hit as lanes sweep d.
    // 128 d * 16 f-quads = 2048 tasks = exactly 8 iterations of 256 threads.
#pragma unroll
    for (int i = 0; i < 8; ++i) {
        int k  = tid + i * 256;
        int d  = k & (EMBED_DIM - 1);
        int fq = k >> 7;                       // 0..15, wave-uniform
        float v[4];
#pragma unroll
        for (int c = 0; c < 4; ++c) {
            int f = fq * 4 + c;
            v[c] = (f < NUM_FIELDS) ? embed_table[(size_t)sidx[f] * EMBED_DIM + d] : 0.f;
        }
        bf16x4 pk = {(__bf16)v[0], (__bf16)v[1], (__bf16)v[2], (__bf16)v[3]};
        int fg  = fq >> 1;
        int grp = (fg + 2 * d) & 7;
        *reinterpret_cast<bf16x4*>(reinterpret_cast<char*>(eT)
            + d * (ET_STRIDE * 2) + grp * 16 + (fq & 1) * 8) = pk;
    }

    float partial = (tid < NUM_FIELDS) ? linear_table[sidx[tid]] : 0.f;
    __syncthreads();

    const int wave = tid >> 6, lane = tid & 63;
    const int m = lane & 15, quad = lane >> 4;

    float pairp = 0.f, trip = 0.f;

    for (int rti = 0; rti < 2; ++rti) {
        const int r = (wave * 2 + rti) * 16 + m;

        // ---- pass 1: W0 pair term (l = 0,1) — small register footprint
        {
            bf16x8 af[2][2];
#pragma unroll
            for (int l = 0; l < 2; ++l) {
                const float* Wrow = W0 + ((size_t)(l * RANK) + r) * NUM_FIELDS;
#pragma unroll
                for (int kc = 0; kc < 2; ++kc)
                    af[l][kc] = load_afrag(Wrow, quad, kc);
            }
            for (int dt = 0; dt < 8; ++dt) {
                const int d = dt * 16 + m;
                bf16x8 bfrag[2];
#pragma unroll
                for (int kc = 0; kc < 2; ++kc) {
                    int grp = ((kc * 4 + quad) + 2 * d) & 7;
                    bfrag[kc] = *reinterpret_cast<const bf16x8*>(
                        reinterpret_cast<const char*>(eT) + d * (ET_STRIDE * 2) + grp * 16);
                }
                f32x4 a0 = {0.f, 0.f, 0.f, 0.f}, a1 = {0.f, 0.f, 0.f, 0.f};
#pragma unroll
                for (int kc = 0; kc < 2; ++kc) {
                    a0 = __builtin_amdgcn_mfma_f32_16x16x32_bf16(af[0][kc], bfrag[kc], a0, 0, 0, 0);
                    a1 = __builtin_amdgcn_mfma_f32_16x16x32_bf16(af[1][kc], bfrag[kc], a1, 0, 0, 0);
                }
#pragma unroll
                for (int i = 0; i < 4; ++i) pairp += a0[i] * a1[i];
            }
        }

        // ---- pass 2: W1 triple term (l = 2,3,4)
        {
            bf16x8 ag[3][2];
#pragma unroll
            for (int l = 0; l < 3; ++l) {
                const float* Wrow = W1 + ((size_t)(l * RANK) + r) * NUM_FIELDS;
#pragma unroll
                for (int kc = 0; kc < 2; ++kc)
                    ag[l][kc] = load_afrag(Wrow, quad, kc);
            }
            for (int dt = 0; dt < 8; ++dt) {
                const int d = dt * 16 + m;
                bf16x8 bfrag[2];
#pragma unroll
                for (int kc = 0; kc < 2; ++kc) {
                    int grp = ((kc * 4 + quad) + 2 * d) & 7;
                    bfrag[kc] = *reinterpret_cast<const bf16x8*>(
                        reinterpret_cast<const char*>(eT) + d * (ET_STRIDE * 2) + grp * 16);
                }
                f32x4 a2 = {0.f, 0.f, 0.f, 0.f}, a3 = {0.f, 0.f, 0.f, 0.f}, a4 = {0.f, 0.f, 0.f, 0.f};
#pragma unroll
                for (int kc = 0; kc < 2; ++kc) {
                    a2 = __builtin_amdgcn_mfma_f32_16x16x32_bf16(ag[0][kc], bfrag[kc], a2, 0, 0, 0);
                    a3 = __builtin_amdgcn_mfma_f32_16x16x32_bf16(ag[1][kc], bfrag[kc], a3, 0, 0, 0);
                    a4 = __builtin_amdgcn_mfma_f32_16x16x32_bf16(ag[2][kc], bfrag[kc], a4, 0, 0, 0);
                }
#pragma unroll
                for (int i = 0; i < 4; ++i) trip += a2[i] * a3[i] * a4[i];
            }
        }
    }

    partial += pairp + trip;

    // Block reduction: wave shuffle -> LDS -> thread 0.
#pragma unroll
    for (int off = 32; off > 0; off >>= 1)
        partial += __shfl_down(partial, off, 64);
    if (lane == 0) wpart[wave] = partial;
    __syncthreads();
    if (tid == 0)
        out[b] = wpart[0] + wpart[1] + wpart[2] + wpart[3] + bias[0];

    // Second tuple output ("0") and trailing pad.
    if (b == 0)
        for (int j = BATCH + tid; j < out_size; j += 256)
            out[j] = 0.f;
}

extern "C" void kernel_launch(void* const* d_in, const int* in_sizes, int n_in,
                              void* d_out, int out_size, void* d_ws, size_t ws_size,
                              hipStream_t stream) {
    const int*   x            = (const int*)d_in[0];
    const float* embed_table  = (const float*)d_in[1];
    const float* linear_table = (const float*)d_in[2];
    const float* bias         = (const float*)d_in[3];
    const float* W0           = (const float*)d_in[4];
    const float* W1           = (const float*)d_in[5];

    tfm_fused<<<BATCH, 256, 0, stream>>>(x, embed_table, linear_table, bias, W0, W1,
                                         (float*)d_out, out_size);
}

// Round 4
// 330.715 us; speedup vs baseline: 1.4763x; 1.4763x over previous
//
#include <hip/hip_runtime.h>
#include <hip/hip_bf16.h>

#define NUM_FIELDS 39
#define PER_FIELD_VOCAB 10000
#define EMBED_DIM 128
#define RANK 128
#define BATCH 2048
#define ET_STRIDE 72   // bf16 elems per d-row: 8 swizzled 16B groups + 1 pad group (144 B)

typedef __bf16 bf16x8 __attribute__((ext_vector_type(8)));
typedef __bf16 bf16x4 __attribute__((ext_vector_type(4)));
typedef float  f32x4  __attribute__((ext_vector_type(4)));
typedef float  f32x4u __attribute__((ext_vector_type(4), aligned(4)));
typedef float  f32x2u __attribute__((ext_vector_type(2), aligned(4)));

// Load one A-fragment (16x16x32 bf16, rows = r, k = f) straight from W (f32,
// row length 39), zero-padded to K=64. kc=0 covers f 0..31 (always valid);
// kc=1 covers f 32..63: only quad==0 has data (f 32..38).
__device__ inline bf16x8 load_afrag(const float* __restrict__ Wrow, int quad, int kc) {
    if (kc == 0) {
        f32x4u a = *reinterpret_cast<const f32x4u*>(Wrow + quad * 8);
        f32x4u b = *reinterpret_cast<const f32x4u*>(Wrow + quad * 8 + 4);
        return (bf16x8){(__bf16)a[0], (__bf16)a[1], (__bf16)a[2], (__bf16)a[3],
                        (__bf16)b[0], (__bf16)b[1], (__bf16)b[2], (__bf16)b[3]};
    }
    if (quad == 0) {   // f = 32..38 valid, f = 39 pad
        f32x4u a = *reinterpret_cast<const f32x4u*>(Wrow + 32);
        f32x2u b = *reinterpret_cast<const f32x2u*>(Wrow + 36);
        float  c = Wrow[38];
        return (bf16x8){(__bf16)a[0], (__bf16)a[1], (__bf16)a[2], (__bf16)a[3],
                        (__bf16)b[0], (__bf16)b[1], (__bf16)c, (__bf16)0.f};
    }
    return (bf16x8){(__bf16)0.f, (__bf16)0.f, (__bf16)0.f, (__bf16)0.f,
                    (__bf16)0.f, (__bf16)0.f, (__bf16)0.f, (__bf16)0.f};
}

// ---------------------------------------------------------------------------
// Single fused kernel: one workgroup (256 thr = 4 waves) per batch element.
//   ret[b] = bias + sum_f linear[idx]
//          + sum_{r,d} dp0*dp1 + sum_{r,d} dp2*dp3*dp4,  dp_l = W_l E
// NOTE: no min-waves in launch_bounds — R2's (256,6) forced a ~85-VGPR budget
// and the compiler spilled ~270 MB/dispatch each way to scratch (the entire
// 281 us was spill traffic). Spill-free > occupancy here; latency hiding
// comes from 8 blocks/CU (LDS-limited), not waves/block.
// ---------------------------------------------------------------------------
__global__ __launch_bounds__(256) void tfm_fused(const int* __restrict__ x,
                                                 const float* __restrict__ embed_table,
                                                 const float* __restrict__ linear_table,
                                                 const float* __restrict__ bias,
                                                 const float* __restrict__ W0,
                                                 const float* __restrict__ W1,
                                                 float* __restrict__ out,
                                                 int out_size) {
    __shared__ int sidx[NUM_FIELDS];
    __shared__ __align__(16) __bf16 eT[EMBED_DIM * ET_STRIDE];  // 18432 B, swizzled
    __shared__ float wpart[4];

    const int tid = threadIdx.x;
    const int b   = blockIdx.x;

    if (tid < NUM_FIELDS)
        sidx[tid] = x[b * NUM_FIELDS + tid] + tid * PER_FIELD_VOCAB;
    __syncthreads();

    // Gather emb -> LDS eT[d][f] (bf16, K zero-padded to 64), group-swizzled:
    // logical 16B group fg of row d lives at physical group (fg + 2d) & 7.
    // 128 d * 16 f-quads = 2048 tasks = exactly 8 iterations of 256 threads.
#pragma unroll
    for (int i = 0; i < 8; ++i) {
        int k  = tid + i * 256;
        int d  = k & (EMBED_DIM - 1);
        int fq = k >> 7;                       // 0..15, wave-uniform
        float v[4];
#pragma unroll
        for (int c = 0; c < 4; ++c) {
            int f = fq * 4 + c;
            v[c] = (f < NUM_FIELDS) ? embed_table[(size_t)sidx[f] * EMBED_DIM + d] : 0.f;
        }
        bf16x4 pk = {(__bf16)v[0], (__bf16)v[1], (__bf16)v[2], (__bf16)v[3]};
        int fg  = fq >> 1;
        int grp = (fg + 2 * d) & 7;
        *reinterpret_cast<bf16x4*>(reinterpret_cast<char*>(eT)
            + d * (ET_STRIDE * 2) + grp * 16 + (fq & 1) * 8) = pk;
    }

    float partial = (tid < NUM_FIELDS) ? linear_table[sidx[tid]] : 0.f;
    __syncthreads();

    const int wave = tid >> 6, lane = tid & 63;
    const int m = lane & 15, quad = lane >> 4;

    float pairp = 0.f, trip = 0.f;

    // Wave owns r-tiles {2w, 2w+1}; single pass over all 5 slabs per d-tile.
    for (int rti = 0; rti < 2; ++rti) {
        const int r = (wave * 2 + rti) * 16 + m;

        bf16x8 af[5][2];
#pragma unroll
        for (int l = 0; l < 2; ++l) {
            const float* Wrow = W0 + ((size_t)(l * RANK) + r) * NUM_FIELDS;
#pragma unroll
            for (int kc = 0; kc < 2; ++kc) af[l][kc] = load_afrag(Wrow, quad, kc);
        }
#pragma unroll
        for (int l = 0; l < 3; ++l) {
            const float* Wrow = W1 + ((size_t)(l * RANK) + r) * NUM_FIELDS;
#pragma unroll
            for (int kc = 0; kc < 2; ++kc) af[2 + l][kc] = load_afrag(Wrow, quad, kc);
        }

        for (int dt = 0; dt < 8; ++dt) {
            const int d = dt * 16 + m;
            bf16x8 bfrag[2];
#pragma unroll
            for (int kc = 0; kc < 2; ++kc) {
                int grp = ((kc * 4 + quad) + 2 * d) & 7;
                bfrag[kc] = *reinterpret_cast<const bf16x8*>(
                    reinterpret_cast<const char*>(eT) + d * (ET_STRIDE * 2) + grp * 16);
            }
            f32x4 acc[5];
#pragma unroll
            for (int l = 0; l < 5; ++l) acc[l] = (f32x4){0.f, 0.f, 0.f, 0.f};
#pragma unroll
            for (int kc = 0; kc < 2; ++kc)
#pragma unroll
                for (int l = 0; l < 5; ++l)
                    acc[l] = __builtin_amdgcn_mfma_f32_16x16x32_bf16(
                        af[l][kc], bfrag[kc], acc[l], 0, 0, 0);
#pragma unroll
            for (int i = 0; i < 4; ++i) {
                pairp += acc[0][i] * acc[1][i];
                trip  += acc[2][i] * acc[3][i] * acc[4][i];
            }
        }
    }

    partial += pairp + trip;

    // Block reduction: wave shuffle -> LDS -> thread 0.
#pragma unroll
    for (int off = 32; off > 0; off >>= 1)
        partial += __shfl_down(partial, off, 64);
    if (lane == 0) wpart[wave] = partial;
    __syncthreads();
    if (tid == 0)
        out[b] = wpart[0] + wpart[1] + wpart[2] + wpart[3] + bias[0];

    // Second tuple output ("0") and trailing pad.
    if (b == 0)
        for (int j = BATCH + tid; j < out_size; j += 256)
            out[j] = 0.f;
}

extern "C" void kernel_launch(void* const* d_in, const int* in_sizes, int n_in,
                              void* d_out, int out_size, void* d_ws, size_t ws_size,
                              hipStream_t stream) {
    const int*   x            = (const int*)d_in[0];
    const float* embed_table  = (const float*)d_in[1];
    const float* linear_table = (const float*)d_in[2];
    const float* bias         = (const float*)d_in[3];
    const float* W0           = (const float*)d_in[4];
    const float* W1           = (const float*)d_in[5];

    tfm_fused<<<BATCH, 256, 0, stream>>>(x, embed_table, linear_table, bias, W0, W1,
                                         (float*)d_out, out_size);
}

// Round 5
// 323.465 us; speedup vs baseline: 1.5094x; 1.0224x over previous
//
#include <hip/hip_runtime.h>
#include <hip/hip_bf16.h>

#define NUM_FIELDS 39
#define PER_FIELD_VOCAB 10000
#define EMBED_DIM 128
#define RANK 128
#define BATCH 2048
#define LDS_ROW 144        // bytes per d-row in gather LDS (64 bf16 + 8 pad)
#define IMG_ROW 128        // bytes per d-row in the ws eT image (64 bf16, K-padded)
#define IMG_BYTES (EMBED_DIM * IMG_ROW)   // 16384 per batch

typedef __bf16 bf16x8 __attribute__((ext_vector_type(8)));
typedef float  f32x4  __attribute__((ext_vector_type(4)));
typedef float  f32x4u __attribute__((ext_vector_type(4), aligned(4)));
typedef float  f32x2u __attribute__((ext_vector_type(2), aligned(4)));

// ---------------------------------------------------------------------------
// Kernel 1: embedding gather + transpose. One block per batch element.
// Writes eT image: ws[b][d][f] bf16, f zero-padded to 64 (16 KB per batch).
// Thread t: d = t&127, half = t>>7; 32 coalesced row loads (one f per load,
// 128 consecutive d across threads), pack to bf16, 4x b128 LDS writes
// (multi-dword -> bank-uniform), then 64 B/thread coalesced global writeback.
// ---------------------------------------------------------------------------
__global__ __launch_bounds__(256) void gather_t(const int* __restrict__ x,
                                                const float* __restrict__ embed_table,
                                                __bf16* __restrict__ ws) {
    __shared__ int sidx[NUM_FIELDS];
    __shared__ __align__(16) char eT[EMBED_DIM * LDS_ROW];   // 18432 B

    const int tid = threadIdx.x, b = blockIdx.x;
    if (tid < NUM_FIELDS)
        sidx[tid] = x[b * NUM_FIELDS + tid] + tid * PER_FIELD_VOCAB;
    __syncthreads();

    const int d = tid & (EMBED_DIM - 1);
    const int half = tid >> 7;               // f range: half*32 .. half*32+31

    float v[32];
#pragma unroll
    for (int j = 0; j < 32; ++j) {
        int f = half * 32 + j;
        v[j] = (f < NUM_FIELDS) ? embed_table[(size_t)sidx[f] * EMBED_DIM + d] : 0.f;
    }
#pragma unroll
    for (int g = 0; g < 4; ++g) {
        bf16x8 pk = {(__bf16)v[g*8+0], (__bf16)v[g*8+1], (__bf16)v[g*8+2], (__bf16)v[g*8+3],
                     (__bf16)v[g*8+4], (__bf16)v[g*8+5], (__bf16)v[g*8+6], (__bf16)v[g*8+7]};
        *reinterpret_cast<bf16x8*>(eT + d * LDS_ROW + half * 64 + g * 16) = pk;
    }
    __syncthreads();

    // Writeback: thread t owns image bytes 64t .. 64t+63 (fully coalesced).
    const int o  = tid * 64;
    const int dd = o >> 7, rest = o & (IMG_ROW - 1);
    char* dst = (char*)ws + (size_t)b * IMG_BYTES + o;
#pragma unroll
    for (int j = 0; j < 4; ++j) {
        uint4 val = *reinterpret_cast<const uint4*>(eT + dd * LDS_ROW + rest + j * 16);
        *reinterpret_cast<uint4*>(dst + j * 16) = val;
    }
}

// Load one A-fragment (16x16x32 bf16, rows = r, k = f) straight from W (f32,
// row length 39), zero-padded to K=64. kc=0 covers f 0..31 (always valid);
// kc=1 covers f 32..63: only quad==0 has data (f 32..38).
__device__ inline bf16x8 load_afrag(const float* __restrict__ Wrow, int quad, int kc) {
    if (kc == 0) {
        f32x4u a = *reinterpret_cast<const f32x4u*>(Wrow + quad * 8);
        f32x4u b = *reinterpret_cast<const f32x4u*>(Wrow + quad * 8 + 4);
        return (bf16x8){(__bf16)a[0], (__bf16)a[1], (__bf16)a[2], (__bf16)a[3],
                        (__bf16)b[0], (__bf16)b[1], (__bf16)b[2], (__bf16)b[3]};
    }
    if (quad == 0) {   // f = 32..38 valid, f = 39 pad
        f32x4u a = *reinterpret_cast<const f32x4u*>(Wrow + 32);
        f32x2u b = *reinterpret_cast<const f32x2u*>(Wrow + 36);
        float  c = Wrow[38];
        return (bf16x8){(__bf16)a[0], (__bf16)a[1], (__bf16)a[2], (__bf16)a[3],
                        (__bf16)b[0], (__bf16)b[1], (__bf16)c, (__bf16)0.f};
    }
    return (bf16x8){(__bf16)0.f, (__bf16)0.f, (__bf16)0.f, (__bf16)0.f,
                    (__bf16)0.f, (__bf16)0.f, (__bf16)0.f, (__bf16)0.f};
}

// ---------------------------------------------------------------------------
// Kernel 2: MFMA compute. One block (4 waves) per batch element.
// B-fragments load DIRECTLY from the staged eT image (16-B loads, stride
// 128 B; each 128-B line is fetched once and fully consumed via L1 across
// quads/kc, reused across rti). No eT LDS, no staging barriers.
// ---------------------------------------------------------------------------
__global__ __launch_bounds__(256) void tfm_compute(const int* __restrict__ x,
                                                   const __bf16* __restrict__ ws,
                                                   const float* __restrict__ linear_table,
                                                   const float* __restrict__ bias,
                                                   const float* __restrict__ W0,
                                                   const float* __restrict__ W1,
                                                   float* __restrict__ out,
                                                   int out_size) {
    __shared__ float wpart[4];

    const int tid = threadIdx.x, b = blockIdx.x;
    const int wave = tid >> 6, lane = tid & 63;
    const int m = lane & 15, quad = lane >> 4;

    float partial = 0.f;
    if (tid < NUM_FIELDS)
        partial = linear_table[x[b * NUM_FIELDS + tid] + tid * PER_FIELD_VOCAB];

    const char* img = (const char*)ws + (size_t)b * IMG_BYTES;

    float pairp = 0.f, trip = 0.f;
    for (int rti = 0; rti < 2; ++rti) {
        const int r = (wave * 2 + rti) * 16 + m;

        bf16x8 af[5][2];
#pragma unroll
        for (int l = 0; l < 2; ++l) {
            const float* Wrow = W0 + ((size_t)(l * RANK) + r) * NUM_FIELDS;
#pragma unroll
            for (int kc = 0; kc < 2; ++kc) af[l][kc] = load_afrag(Wrow, quad, kc);
        }
#pragma unroll
        for (int l = 0; l < 3; ++l) {
            const float* Wrow = W1 + ((size_t)(l * RANK) + r) * NUM_FIELDS;
#pragma unroll
            for (int kc = 0; kc < 2; ++kc) af[2 + l][kc] = load_afrag(Wrow, quad, kc);
        }

        for (int dt = 0; dt < 8; ++dt) {
            const int d = dt * 16 + m;
            bf16x8 bfrag[2];
#pragma unroll
            for (int kc = 0; kc < 2; ++kc)
                bfrag[kc] = *reinterpret_cast<const bf16x8*>(
                    img + d * IMG_ROW + kc * 64 + quad * 16);

            f32x4 acc[5];
#pragma unroll
            for (int l = 0; l < 5; ++l) acc[l] = (f32x4){0.f, 0.f, 0.f, 0.f};
#pragma unroll
            for (int kc = 0; kc < 2; ++kc)
#pragma unroll
                for (int l = 0; l < 5; ++l)
                    acc[l] = __builtin_amdgcn_mfma_f32_16x16x32_bf16(
                        af[l][kc], bfrag[kc], acc[l], 0, 0, 0);
#pragma unroll
            for (int i = 0; i < 4; ++i) {
                pairp += acc[0][i] * acc[1][i];
                trip  += acc[2][i] * acc[3][i] * acc[4][i];
            }
        }
    }
    partial += pairp + trip;

    // Block reduction: wave shuffle -> LDS -> thread 0.
#pragma unroll
    for (int off = 32; off > 0; off >>= 1)
        partial += __shfl_down(partial, off, 64);
    if (lane == 0) wpart[wave] = partial;
    __syncthreads();
    if (tid == 0)
        out[b] = wpart[0] + wpart[1] + wpart[2] + wpart[3] + bias[0];

    // Second tuple output ("0") and trailing pad.
    if (b == 0)
        for (int j = BATCH + tid; j < out_size; j += 256)
            out[j] = 0.f;
}

extern "C" void kernel_launch(void* const* d_in, const int* in_sizes, int n_in,
                              void* d_out, int out_size, void* d_ws, size_t ws_size,
                              hipStream_t stream) {
    const int*   x            = (const int*)d_in[0];
    const float* embed_table  = (const float*)d_in[1];
    const float* linear_table = (const float*)d_in[2];
    const float* bias         = (const float*)d_in[3];
    const float* W0           = (const float*)d_in[4];
    const float* W1           = (const float*)d_in[5];
    __bf16* ws = (__bf16*)d_ws;   // eT images: 2048 * 16384 B = 32 MB

    gather_t<<<BATCH, 256, 0, stream>>>(x, embed_table, ws);
    tfm_compute<<<BATCH, 256, 0, stream>>>(x, ws, linear_table, bias, W0, W1,
                                           (float*)d_out, out_size);
}

// Round 6
// 287.642 us; speedup vs baseline: 1.6974x; 1.1245x over previous
//
#include <hip/hip_runtime.h>
#include <hip/hip_bf16.h>

#define NUM_FIELDS 39
#define PER_FIELD_VOCAB 10000
#define EMBED_DIM 128
#define KPAD 64          // F padded to 64: two K=32 MFMA chunks
#define NL 5             // 2 (W0 pair) + 3 (W1 triple)
#define RANK 128
#define BATCH 2048
#define ET_ROW 144       // bytes per d-row in LDS: 8 x 16B swizzled groups + 16B pad

typedef __bf16 bf16x8 __attribute__((ext_vector_type(8)));
typedef __bf16 bf16x4 __attribute__((ext_vector_type(4)));
typedef float  f32x4  __attribute__((ext_vector_type(4)));

// ---------------------------------------------------------------------------
// Prep: W0 [2,128,39] f32 + W1 [3,128,39] f32 -> Wb [5][128][64] bf16
// (zero-padded in f). Pre-packing keeps the main loop's A-fragment path as
// clean 16-B aligned vector loads with zero conversion ALU — R3/R4 showed the
// in-loop f32->bf16 convert costs ~50 us via pressure + VALU.
// ---------------------------------------------------------------------------
__global__ __launch_bounds__(256) void prep_w(const float* __restrict__ W0,
                                              const float* __restrict__ W1,
                                              __bf16* __restrict__ Wb) {
    int i = blockIdx.x * 256 + threadIdx.x;       // 5*128*64 = 40960
    if (i >= NL * RANK * KPAD) return;
    int f = i & (KPAD - 1);
    int r = (i >> 6) & (RANK - 1);
    int l = i >> 13;
    float v = 0.f;
    if (f < NUM_FIELDS) {
        if (l < 2) v = W0[(l * RANK + r) * NUM_FIELDS + f];
        else       v = W1[((l - 2) * RANK + r) * NUM_FIELDS + f];
    }
    Wb[i] = (__bf16)v;
}

// ---------------------------------------------------------------------------
// Main: one workgroup (256 thr = 4 waves) per batch element.
//   ret[b] = bias + sum_f linear[idx]
//          + sum_{r,d} dp0*dp1 + sum_{r,d} dp2*dp3*dp4,  dp_l = W_l E
// Gather phase: packed bf16x4 LDS writes, group-swizzled (logical 16B group
// fg of row d stored at physical group (fg+2d)&7) -> uniform bank spread for
// both the b64 writes and the b128 MFMA-phase reads. Zero-pad folded in.
// No launch_bounds min-waves (R2: forcing occupancy caused 860 MB spill).
// ---------------------------------------------------------------------------
__global__ __launch_bounds__(256) void tfm_main(const int* __restrict__ x,
                                                const float* __restrict__ embed_table,
                                                const float* __restrict__ linear_table,
                                                const float* __restrict__ bias,
                                                const __bf16* __restrict__ Wb,
                                                float* __restrict__ out,
                                                int out_size) {
    __shared__ int sidx[NUM_FIELDS];
    __shared__ __align__(16) char eT[EMBED_DIM * ET_ROW];   // 18432 B
    __shared__ float wpart[4];

    const int tid = threadIdx.x;
    const int b   = blockIdx.x;

    if (tid < NUM_FIELDS)
        sidx[tid] = x[b * NUM_FIELDS + tid] + tid * PER_FIELD_VOCAB;
    __syncthreads();

    // 128 d x 16 f-quads = 2048 tasks = exactly 8 iterations of 256 threads.
    // Lanes sweep d at fixed f-quad -> each row read is 4B/lane coalesced.
#pragma unroll
    for (int i = 0; i < 8; ++i) {
        int k  = tid + i * 256;
        int d  = k & (EMBED_DIM - 1);
        int fq = k >> 7;                       // 0..15, wave-uniform
        float v[4];
#pragma unroll
        for (int c = 0; c < 4; ++c) {
            int f = fq * 4 + c;
            v[c] = (f < NUM_FIELDS) ? embed_table[(size_t)sidx[f] * EMBED_DIM + d] : 0.f;
        }
        bf16x4 pk = {(__bf16)v[0], (__bf16)v[1], (__bf16)v[2], (__bf16)v[3]};
        int fg  = fq >> 1;
        int grp = (fg + 2 * d) & 7;
        *reinterpret_cast<bf16x4*>(eT + d * ET_ROW + grp * 16 + (fq & 1) * 8) = pk;
    }

    float partial = (tid < NUM_FIELDS) ? linear_table[sidx[tid]] : 0.f;
    __syncthreads();

    const int wave = tid >> 6, lane = tid & 63;
    const int m = lane & 15, quad = lane >> 4;

    float pairp = 0.f, trip = 0.f;

    // Wave owns r-tiles {2w, 2w+1}; single pass, 5 accumulators (R0 pattern:
    // af[5][2]=40 VGPR held + 20 acc -> ~85 total, ~5 waves/SIMD, no spill).
    for (int rti = 0; rti < 2; ++rti) {
        const int r = (wave * 2 + rti) * 16 + m;

        bf16x8 af[NL][2];
#pragma unroll
        for (int l = 0; l < NL; ++l)
#pragma unroll
            for (int kc = 0; kc < 2; ++kc)
                af[l][kc] = *reinterpret_cast<const bf16x8*>(
                    &Wb[((size_t)(l * RANK) + r) * KPAD + kc * 32 + quad * 8]);

        for (int dt = 0; dt < 8; ++dt) {
            const int d = dt * 16 + m;
            bf16x8 bfrag[2];
#pragma unroll
            for (int kc = 0; kc < 2; ++kc) {
                int grp = ((kc * 4 + quad) + 2 * d) & 7;
                bfrag[kc] = *reinterpret_cast<const bf16x8*>(eT + d * ET_ROW + grp * 16);
            }
            f32x4 acc[NL];
#pragma unroll
            for (int l = 0; l < NL; ++l) acc[l] = (f32x4){0.f, 0.f, 0.f, 0.f};
#pragma unroll
            for (int kc = 0; kc < 2; ++kc)
#pragma unroll
                for (int l = 0; l < NL; ++l)
                    acc[l] = __builtin_amdgcn_mfma_f32_16x16x32_bf16(
                        af[l][kc], bfrag[kc], acc[l], 0, 0, 0);
#pragma unroll
            for (int i = 0; i < 4; ++i) {
                pairp += acc[0][i] * acc[1][i];
                trip  += acc[2][i] * acc[3][i] * acc[4][i];
            }
        }
    }

    partial += pairp + trip;

    // Block reduction: wave shuffle -> LDS -> thread 0.
#pragma unroll
    for (int off = 32; off > 0; off >>= 1)
        partial += __shfl_down(partial, off, 64);
    if (lane == 0) wpart[wave] = partial;
    __syncthreads();
    if (tid == 0)
        out[b] = wpart[0] + wpart[1] + wpart[2] + wpart[3] + bias[0];

    // Second tuple output ("0") and trailing pad.
    if (b == 0)
        for (int j = BATCH + tid; j < out_size; j += 256)
            out[j] = 0.f;
}

extern "C" void kernel_launch(void* const* d_in, const int* in_sizes, int n_in,
                              void* d_out, int out_size, void* d_ws, size_t ws_size,
                              hipStream_t stream) {
    const int*   x            = (const int*)d_in[0];
    const float* embed_table  = (const float*)d_in[1];
    const float* linear_table = (const float*)d_in[2];
    const float* bias         = (const float*)d_in[3];
    const float* W0           = (const float*)d_in[4];
    const float* W1           = (const float*)d_in[5];
    __bf16* Wb = (__bf16*)d_ws;   // 5*128*64*2 = 81920 B

    prep_w<<<(NL * RANK * KPAD + 255) / 256, 256, 0, stream>>>(W0, W1, Wb);
    tfm_main<<<BATCH, 256, 0, stream>>>(x, embed_table, linear_table, bias, Wb,
                                        (float*)d_out, out_size);
}